// Round 12
// baseline (383.432 us; speedup 1.0000x reference)
//
#include <hip/hip_runtime.h>
#include <hip/hip_bf16.h>

#define D 128
#define AGG_BLOCKS 2048
#define NSHARD 16

typedef __attribute__((ext_vector_type(8))) short short8;
typedef __attribute__((ext_vector_type(4))) float f32x4;

// pack two f32 -> bf16 pair (RNE)
__device__ inline unsigned bf16pair(float x, float y) {
    unsigned xb = __float_as_uint(x), yb = __float_as_uint(y);
    xb = (xb + 0x7FFFu + ((xb >> 16) & 1u)) >> 16;
    yb = (yb + 0x7FFFu + ((yb >> 16) & 1u)) >> 16;
    return xb | (yb << 16);
}

// ---------------------------------------------------------------- pass 0: 256-bin histogram of dst>>8
__global__ void hist_kernel(const int* __restrict__ dst_idx,
                            int* __restrict__ bucket_cnt, int E, int N) {
    __shared__ int h[256];
    int t = threadIdx.x;
    h[t] = 0;
    __syncthreads();
    int e = blockIdx.x * blockDim.x + t;
    int stride = gridDim.x * blockDim.x;
    for (; e < E; e += stride) {
        int d = dst_idx[e];
        if ((unsigned)d < (unsigned)N) atomicAdd(&h[d >> 8], 1);
    }
    __syncthreads();
    if (h[t]) atomicAdd(&bucket_cnt[t], h[t]);
}

// ---------------------------------------------------------------- scan 256 buckets
__global__ void bucket_scan_kernel(const int* __restrict__ bucket_cnt,
                                   int* __restrict__ bucket_base,
                                   int* __restrict__ bucket_cursor,
                                   int* __restrict__ row_ptr, int N) {
    __shared__ int s[256];
    int t = threadIdx.x;
    s[t] = bucket_cnt[t];
    __syncthreads();
    for (int off = 1; off < 256; off <<= 1) {
        int v = (t >= off) ? s[t - off] : 0;
        __syncthreads();
        s[t] += v;
        __syncthreads();
    }
    int ex = t ? s[t - 1] : 0;
    bucket_base[t]   = ex;
    bucket_cursor[t] = ex;
    if (t == 255) { bucket_base[256] = s[255]; row_ptr[N] = s[255]; }
}

// ---------------------------------------------------------------- pass 1: chunked scatter into coarse buckets
#define CH 1024
__global__ void pass1_kernel(const int* __restrict__ idx,
                             const float* __restrict__ w,
                             int* __restrict__ bucket_cursor,
                             int2* __restrict__ rec, int E, int N) {
    __shared__ int h[256], bb[256], cur[256];
    const int* dst = idx + E;
    int t = threadIdx.x;
    int nchunks = (E + CH - 1) / CH;
    for (int c = blockIdx.x; c < nchunks; c += gridDim.x) {
        int lo = c * CH;
        int hi = lo + CH; if (hi > E) hi = E;
        h[t] = 0; cur[t] = 0;
        __syncthreads();
        for (int e = lo + t; e < hi; e += 256) {
            int d = dst[e];
            if ((unsigned)d < (unsigned)N) atomicAdd(&h[d >> 8], 1);
        }
        __syncthreads();
        if (h[t]) bb[t] = atomicAdd(&bucket_cursor[t], h[t]);
        __syncthreads();
        for (int e = lo + t; e < hi; e += 256) {
            int d = dst[e];
            if ((unsigned)d >= (unsigned)N) continue;
            int s = idx[e];
            int b = d >> 8;
            int r = atomicAdd(&cur[b], 1);
            rec[bb[b] + r] = make_int2((s & 0xFFFF) | ((d & 255) << 16),
                                       __float_as_int(w[e]));
        }
        __syncthreads();
    }
}

// ---------------------------------------------------------------- pass 2: per-bucket LDS counting sort -> CSR (raw w) + row_ptr + dinv
__global__ void pass2_kernel(const int2* __restrict__ rec,
                             const int* __restrict__ bucket_base,
                             int2* __restrict__ csr,
                             int* __restrict__ row_ptr,
                             float* __restrict__ dinv, int N) {
    __shared__ int   hist[256], pref[256], cur[256];
    __shared__ float degs[256];
    int b = blockIdx.x;
    int t = threadIdx.x;
    int lo = bucket_base[b], hi = bucket_base[b + 1];
    if (t < 256) { hist[t] = 0; cur[t] = 0; degs[t] = 0.f; }
    __syncthreads();
    for (int e = lo + t; e < hi; e += blockDim.x)
        atomicAdd(&hist[(rec[e].x >> 16) & 255], 1);
    __syncthreads();
    for (int off = 1; off < 256; off <<= 1) {
        int v = 0;
        if (t < 256 && t >= off) v = hist[t - off];
        __syncthreads();
        if (t < 256) hist[t] += v;
        __syncthreads();
    }
    if (t < 256) {
        pref[t] = t ? hist[t - 1] : 0;
        int node = b * 256 + t;
        if (node < N) row_ptr[node] = lo + pref[t];
    }
    __syncthreads();
    for (int e = lo + t; e < hi; e += blockDim.x) {
        int2 rc = rec[e];
        int dl = (rc.x >> 16) & 255;
        int r = atomicAdd(&cur[dl], 1);
        csr[lo + pref[dl] + r] = rc;
        atomicAdd(&degs[dl], __int_as_float(rc.y));
    }
    __syncthreads();
    if (t < 256) {
        int node = b * 256 + t;
        if (node < N) {
            float dg = degs[t];
            dinv[node] = (dg > 0.f) ? rsqrtf(dg) : 0.f;
        }
    }
}

// ---------------------------------------------------------------- MFMA GEMM: outb = bf16pack( dinv[row] * act(H) @ Wl )
__global__ __launch_bounds__(256, 2)
void gemm_mfma_kernel(const float* __restrict__ H, const float* __restrict__ Wl,
                      const float* __restrict__ AB, const float* __restrict__ dinv,
                      unsigned* __restrict__ outb, int n) {
    __shared__ __align__(16) unsigned short Wt[128][136];  // W^T, padded
    __shared__ __align__(16) unsigned short As[64][136];   // A tile, padded
    int t = threadIdx.x;
    int w = t >> 6, l = t & 63;
    int col16 = l & 15, grp = l >> 4;

    // stage W^T as bf16 (one time)
    for (int i = t; i < 128 * 128; i += 256) {
        int k = i >> 7, j = i & 127;
        Wt[j][k] = (unsigned short)(bf16pair(Wl[i], 0.f) & 0xFFFFu);
    }
    __syncthreads();

    // hoist B-fragments: 8 n-tiles x 4 k-blocks
    short8 bfrag[8][4];
    #pragma unroll
    for (int tt = 0; tt < 8; tt++)
        #pragma unroll
        for (int kb = 0; kb < 4; kb++)
            bfrag[tt][kb] = *(const short8*)&Wt[tt * 16 + col16][kb * 32 + grp * 8];

    int ntiles = (n + 63) >> 6;
    for (int tile = blockIdx.x; tile < ntiles; tile += gridDim.x) {
        int base = tile << 6;
        __syncthreads();   // prior a-frag reads done before overwrite
        // stage A: 64 rows x 128 cols, fused act, bf16 pack
        for (int i = t; i < 64 * 32; i += 256) {
            int rr = i >> 5, cc = (i & 31) * 4;
            int row = base + rr;
            float4 v = make_float4(0.f, 0.f, 0.f, 0.f);
            if (row < n) v = *(const float4*)(H + (size_t)row * D + cc);
            if (AB) {
                float4 A = *(const float4*)(AB + cc);
                float4 B = *(const float4*)(AB + 128 + cc);
                v.x = fmaxf(fmaf(v.x, A.x, B.x), 0.f);
                v.y = fmaxf(fmaf(v.y, A.y, B.y), 0.f);
                v.z = fmaxf(fmaf(v.z, A.z, B.z), 0.f);
                v.w = fmaxf(fmaf(v.w, A.w, B.w), 0.f);
            }
            *(uint2*)&As[rr][cc] = make_uint2(bf16pair(v.x, v.y), bf16pair(v.z, v.w));
        }
        __syncthreads();

        // a-fragments for this wave's 16 rows
        int rowb = w * 16;
        short8 afrag[4];
        #pragma unroll
        for (int kb = 0; kb < 4; kb++)
            afrag[kb] = *(const short8*)&As[rowb + col16][kb * 32 + grp * 8];

        // per-output-row dinv (fold src-side GCN norm into the table)
        float dv[4];
        #pragma unroll
        for (int r = 0; r < 4; r++) {
            int row = base + rowb + grp * 4 + r;
            dv[r] = (row < n) ? dinv[row] : 0.f;
        }

        #pragma unroll
        for (int tt = 0; tt < 8; tt++) {
            f32x4 acc = {0.f, 0.f, 0.f, 0.f};
            #pragma unroll
            for (int kb = 0; kb < 4; kb++)
                acc = __builtin_amdgcn_mfma_f32_16x16x32_bf16(afrag[kb], bfrag[tt][kb], acc, 0, 0, 0);
            #pragma unroll
            for (int r = 0; r < 4; r++) {
                float v = acc[r] * dv[r];
                float nb = __shfl_xor(v, 1);
                if (!(l & 1)) {
                    int row = base + rowb + grp * 4 + r;
                    if (row < n)
                        outb[(size_t)row * 64 + tt * 8 + (col16 >> 1)] = bf16pair(v, nb);
                }
            }
        }
    }
}

// ---------------------------------------------------------------- pull aggregation + bias + residual + col-stats
// ping-pong gather pipeline: batch k+1's 8 gathers issued before batch k consumed (16 in flight).
#define CSRLOAD(P, eb) \
    P##0 = csr_ew[(eb) + 0]; P##1 = csr_ew[(eb) + 1]; \
    P##2 = csr_ew[(eb) + 2]; P##3 = csr_ew[(eb) + 3]; \
    P##4 = csr_ew[(eb) + 4]; P##5 = csr_ew[(eb) + 5]; \
    P##6 = csr_ew[(eb) + 6]; P##7 = csr_ew[(eb) + 7];
#define GISSUE(G, P) \
    G##0 = xlb[(size_t)((P##0).x & 0xFFFF) * 64 + lane]; \
    G##1 = xlb[(size_t)((P##1).x & 0xFFFF) * 64 + lane]; \
    G##2 = xlb[(size_t)((P##2).x & 0xFFFF) * 64 + lane]; \
    G##3 = xlb[(size_t)((P##3).x & 0xFFFF) * 64 + lane]; \
    G##4 = xlb[(size_t)((P##4).x & 0xFFFF) * 64 + lane]; \
    G##5 = xlb[(size_t)((P##5).x & 0xFFFF) * 64 + lane]; \
    G##6 = xlb[(size_t)((P##6).x & 0xFFFF) * 64 + lane]; \
    G##7 = xlb[(size_t)((P##7).x & 0xFFFF) * 64 + lane];
#define CONS1(G, P, A) { float wv = __int_as_float((P).y); \
    A##0 += wv * __uint_as_float((G) << 16); \
    A##1 += wv * __uint_as_float((G) & 0xFFFF0000u); }
#define CONSUME(G, P) \
    CONS1(G##0, P##0, pa) CONS1(G##1, P##1, pb) \
    CONS1(G##2, P##2, pc) CONS1(G##3, P##3, pd) \
    CONS1(G##4, P##4, pa) CONS1(G##5, P##5, pb) \
    CONS1(G##6, P##6, pc) CONS1(G##7, P##7, pd)

__global__ __launch_bounds__(256, 7)
void agg_kernel(const unsigned* __restrict__ xlb,
                const int* __restrict__ row_ptr,
                const int2* __restrict__ csr_ew,
                const float* __restrict__ dinv,
                const float* __restrict__ bvec,
                float* __restrict__ hr,        // in(res)/out, f32
                float* __restrict__ stats,     // [NSHARD][256]: sum | sumsq (atomic)
                int n, int has_res) {
    int wave = threadIdx.x >> 6;
    int lane = threadIdx.x & 63;
    int wid = blockIdx.x * 4 + wave;
    int nw = gridDim.x * 4;
    int chunk = (n + nw - 1) / nw;
    int r0 = wid * chunk;
    int r1 = r0 + chunk; if (r1 > n) r1 = n;

    float bb0 = bvec[lane * 2], bb1 = bvec[lane * 2 + 1];
    float s0 = 0.f, s1 = 0.f, q0 = 0.f, q1 = 0.f;

    for (int i = r0; i < r1; i++) {
        int beg = __builtin_amdgcn_readfirstlane(row_ptr[i]);
        int end = __builtin_amdgcn_readfirstlane(row_ptr[i + 1]);
        float di = __uint_as_float(
            (unsigned)__builtin_amdgcn_readfirstlane(__float_as_uint(dinv[i])));
        float pa0 = 0.f, pa1 = 0.f, pb0 = 0.f, pb1 = 0.f;
        float pc0 = 0.f, pc1 = 0.f, pd0 = 0.f, pd1 = 0.f;
        int nb = (end - beg) >> 3;           // full 8-edge batches
        int2 ca0, ca1, ca2, ca3, ca4, ca5, ca6, ca7;
        int2 cb0, cb1, cb2, cb3, cb4, cb5, cb6, cb7;
        unsigned ga0, ga1, ga2, ga3, ga4, ga5, ga6, ga7;
        unsigned gb0, gb1, gb2, gb3, gb4, gb5, gb6, gb7;
        if (nb > 0) {
            CSRLOAD(ca, beg)
            GISSUE(ga, ca)
        }
        int k = 0;
        while (k < nb) {
            // bank B: load csr + issue gathers for batch k+1
            if (k + 1 < nb) {
                CSRLOAD(cb, beg + (k + 1) * 8)
                GISSUE(gb, cb)
            }
            CONSUME(ga, ca)          // waits only on bank A's gathers
            k++;
            if (k >= nb) break;
            // bank A: load csr + issue gathers for batch k+1
            if (k + 1 < nb) {
                CSRLOAD(ca, beg + (k + 1) * 8)
                GISSUE(ga, ca)
            }
            CONSUME(gb, cb)
            k++;
        }
        for (int e = beg + nb * 8; e < end; e++) {
            int2 c = csr_ew[e];
            float wv = __int_as_float(c.y);
            unsigned g = xlb[(size_t)(c.x & 0xFFFF) * 64 + lane];
            pa0 += wv * __uint_as_float(g << 16);
            pa1 += wv * __uint_as_float(g & 0xFFFF0000u);
        }
        float a0 = ((pa0 + pb0) + (pc0 + pd0)) * di + bb0;
        float a1 = ((pa1 + pb1) + (pc1 + pd1)) * di + bb1;
        if (has_res) {
            float2 rr = *(const float2*)(hr + (size_t)i * D + lane * 2);
            a0 += rr.x; a1 += rr.y;
        }
        *(float2*)(hr + (size_t)i * D + lane * 2) = make_float2(a0, a1);
        s0 += a0; s1 += a1;
        q0 += a0 * a0; q1 += a1 * a1;
    }

    __shared__ float redS[4][D];
    __shared__ float redQ[4][D];
    redS[wave][lane * 2] = s0; redS[wave][lane * 2 + 1] = s1;
    redQ[wave][lane * 2] = q0; redQ[wave][lane * 2 + 1] = q1;
    __syncthreads();
    int t = threadIdx.x;
    float* sh = stats + (size_t)(blockIdx.x & (NSHARD - 1)) * 256;
    if (t < 128) {
        atomicAdd(&sh[t], redS[0][t] + redS[1][t] + redS[2][t] + redS[3][t]);
    } else {
        int c = t - 128;
        atomicAdd(&sh[128 + c], redQ[0][c] + redQ[1][c] + redQ[2][c] + redQ[3][c]);
    }
}

// ---------------------------------------------------------------- finalize stats (sum shards) -> per-col scale/shift
__global__ void finalize_kernel(const float* __restrict__ stats,
                                const float* __restrict__ gamma_l,
                                const float* __restrict__ beta_l,
                                float* __restrict__ AB, float n_inv) {
    int t = threadIdx.x; // 128
    if (t < 128) {
        float sum = 0.f, sq = 0.f;
        #pragma unroll
        for (int s = 0; s < NSHARD; s++) {
            sum += stats[s * 256 + t];
            sq  += stats[s * 256 + 128 + t];
        }
        float mean = sum * n_inv;
        float var  = sq * n_inv - mean * mean;
        var = fmaxf(var, 0.f);
        float rstd = rsqrtf(var + 1e-5f);
        float A = rstd * gamma_l[t];
        float B = beta_l[t] - mean * A;
        AB[t] = A;
        AB[128 + t] = B;
    }
}

// ---------------------------------------------------------------- normalize + relu (final layer only)
__global__ void norm_relu_kernel(const float* __restrict__ hr, const float* __restrict__ AB,
                                 float* __restrict__ hout, int total4) {
    int idx = blockIdx.x * blockDim.x + threadIdx.x;
    int stride = gridDim.x * blockDim.x;
    for (; idx < total4; idx += stride) {
        int c4 = (idx & 31) * 4;
        float4 v = ((const float4*)hr)[idx];
        float4 A = *(const float4*)(AB + c4);
        float4 B = *(const float4*)(AB + 128 + c4);
        v.x = fmaxf(fmaf(v.x, A.x, B.x), 0.f);
        v.y = fmaxf(fmaf(v.y, A.y, B.y), 0.f);
        v.z = fmaxf(fmaf(v.z, A.z, B.z), 0.f);
        v.w = fmaxf(fmaf(v.w, A.w, B.w), 0.f);
        ((float4*)hout)[idx] = v;
    }
}

// ================================================================ launch
extern "C" void kernel_launch(void* const* d_in, const int* in_sizes, int n_in,
                              void* d_out, int out_size, void* d_ws, size_t ws_size,
                              hipStream_t stream) {
    const float* x    = (const float*)d_in[0];
    const int*   eidx = (const int*)d_in[1];
    const float* ew   = (const float*)d_in[2];
    const float* W    = (const float*)d_in[3];
    const float* b    = (const float*)d_in[4];
    const float* gmm  = (const float*)d_in[5];
    const float* bet  = (const float*)d_in[6];

    const int N = in_sizes[0] / D;
    const int E = in_sizes[2];
    const int L = in_sizes[4] / D;
    const int NB = (N + 255) >> 8;
    const int NTILE = (N + 63) >> 6;

    size_t off = 0;
    auto carve = [&](size_t bytes) -> void* {
        void* p = (char*)d_ws + off;
        off += (bytes + 255) & ~(size_t)255;
        return p;
    };
    float*    dinv       = (float*)carve((size_t)N * 4);
    int*      row_ptr    = (int*)  carve((size_t)(N + 1) * 4);
    int*      bucket_cnt = (int*)  carve(256 * 4);
    int*      bucket_base= (int*)  carve(257 * 4);
    int*      bucket_cur = (int*)  carve(256 * 4);
    int2*     csr_ew     = (int2*) carve((size_t)E * 8);
    unsigned* xlb        = (unsigned*)carve((size_t)N * 64 * 4);
    float*    hr         = (float*)carve((size_t)N * D * 4);
    float*    stats      = (float*)carve((size_t)L * NSHARD * 256 * 4);
    float*    ABbuf      = (float*)carve((size_t)L * 256 * 4);
    if (off > ws_size) return;

    int2* rec = (int2*)hr;           // pass-1 intermediate overlays hr
    float* hout = (float*)d_out;

    hipMemsetAsync(bucket_cnt, 0, 256 * 4, stream);
    hipMemsetAsync(stats, 0, (size_t)L * NSHARD * 256 * 4, stream);
    hist_kernel<<<1024, 256, 0, stream>>>(eidx + E, bucket_cnt, E, N);
    bucket_scan_kernel<<<1, 256, 0, stream>>>(bucket_cnt, bucket_base, bucket_cur, row_ptr, N);
    pass1_kernel<<<1024, 256, 0, stream>>>(eidx, ew, bucket_cur, rec, E, N);
    pass2_kernel<<<NB, 1024, 0, stream>>>(rec, bucket_base, csr_ew, row_ptr, dinv, N);

    const float n_inv = 1.f / (float)N;
    for (int l = 0; l < L; l++) {
        const float* Hin = (l == 0) ? x : hr;
        const float* ABl = (l == 0) ? nullptr : ABbuf + (size_t)(l - 1) * 256;
        gemm_mfma_kernel<<<NTILE, 256, 0, stream>>>(Hin, W + (size_t)l * D * D, ABl, dinv, xlb, N);
        agg_kernel<<<AGG_BLOCKS, 256, 0, stream>>>(xlb, row_ptr, csr_ew, dinv,
                                                   b + (size_t)l * D, hr,
                                                   stats + (size_t)l * NSHARD * 256,
                                                   N, l > 0 ? 1 : 0);
        finalize_kernel<<<1, 128, 0, stream>>>(stats + (size_t)l * NSHARD * 256,
                                               gmm + (size_t)l * D, bet + (size_t)l * D,
                                               ABbuf + (size_t)l * 256, n_inv);
    }
    norm_relu_kernel<<<1024, 256, 0, stream>>>(hr, ABbuf + (size_t)(L - 1) * 256,
                                               hout, N * (D / 4));
}

// Round 13
// 346.573 us; speedup vs baseline: 1.1064x; 1.1064x over previous
//
#include <hip/hip_runtime.h>
#include <hip/hip_bf16.h>

#define D 128
#define AGG_BLOCKS 2048
#define NSHARD 16

typedef __attribute__((ext_vector_type(8))) short short8;
typedef __attribute__((ext_vector_type(4))) float f32x4;

// pack two f32 -> bf16 pair (RNE)
__device__ inline unsigned bf16pair(float x, float y) {
    unsigned xb = __float_as_uint(x), yb = __float_as_uint(y);
    xb = (xb + 0x7FFFu + ((xb >> 16) & 1u)) >> 16;
    yb = (yb + 0x7FFFu + ((yb >> 16) & 1u)) >> 16;
    return xb | (yb << 16);
}

// ---------------------------------------------------------------- pass 0: 256-bin histogram of dst>>8
__global__ void hist_kernel(const int* __restrict__ dst_idx,
                            int* __restrict__ bucket_cnt, int E, int N) {
    __shared__ int h[256];
    int t = threadIdx.x;
    h[t] = 0;
    __syncthreads();
    int e = blockIdx.x * blockDim.x + t;
    int stride = gridDim.x * blockDim.x;
    for (; e < E; e += stride) {
        int d = dst_idx[e];
        if ((unsigned)d < (unsigned)N) atomicAdd(&h[d >> 8], 1);
    }
    __syncthreads();
    if (h[t]) atomicAdd(&bucket_cnt[t], h[t]);
}

// ---------------------------------------------------------------- scan 256 buckets
__global__ void bucket_scan_kernel(const int* __restrict__ bucket_cnt,
                                   int* __restrict__ bucket_base,
                                   int* __restrict__ bucket_cursor,
                                   int* __restrict__ row_ptr, int N) {
    __shared__ int s[256];
    int t = threadIdx.x;
    s[t] = bucket_cnt[t];
    __syncthreads();
    for (int off = 1; off < 256; off <<= 1) {
        int v = (t >= off) ? s[t - off] : 0;
        __syncthreads();
        s[t] += v;
        __syncthreads();
    }
    int ex = t ? s[t - 1] : 0;
    bucket_base[t]   = ex;
    bucket_cursor[t] = ex;
    if (t == 255) { bucket_base[256] = s[255]; row_ptr[N] = s[255]; }
}

// ---------------------------------------------------------------- pass 1: chunked scatter into coarse buckets
#define CH 1024
__global__ void pass1_kernel(const int* __restrict__ idx,
                             const float* __restrict__ w,
                             int* __restrict__ bucket_cursor,
                             int2* __restrict__ rec, int E, int N) {
    __shared__ int h[256], bb[256], cur[256];
    const int* dst = idx + E;
    int t = threadIdx.x;
    int nchunks = (E + CH - 1) / CH;
    for (int c = blockIdx.x; c < nchunks; c += gridDim.x) {
        int lo = c * CH;
        int hi = lo + CH; if (hi > E) hi = E;
        h[t] = 0; cur[t] = 0;
        __syncthreads();
        for (int e = lo + t; e < hi; e += 256) {
            int d = dst[e];
            if ((unsigned)d < (unsigned)N) atomicAdd(&h[d >> 8], 1);
        }
        __syncthreads();
        if (h[t]) bb[t] = atomicAdd(&bucket_cursor[t], h[t]);
        __syncthreads();
        for (int e = lo + t; e < hi; e += 256) {
            int d = dst[e];
            if ((unsigned)d >= (unsigned)N) continue;
            int s = idx[e];
            int b = d >> 8;
            int r = atomicAdd(&cur[b], 1);
            rec[bb[b] + r] = make_int2((s & 0xFFFF) | ((d & 255) << 16),
                                       __float_as_int(w[e]));
        }
        __syncthreads();
    }
}

// ---------------------------------------------------------------- pass 2: per-bucket LDS counting sort -> CSR (raw w) + row_ptr + dinv
__global__ void pass2_kernel(const int2* __restrict__ rec,
                             const int* __restrict__ bucket_base,
                             int2* __restrict__ csr,
                             int* __restrict__ row_ptr,
                             float* __restrict__ dinv, int N) {
    __shared__ int   hist[256], pref[256], cur[256];
    __shared__ float degs[256];
    int b = blockIdx.x;
    int t = threadIdx.x;
    int lo = bucket_base[b], hi = bucket_base[b + 1];
    if (t < 256) { hist[t] = 0; cur[t] = 0; degs[t] = 0.f; }
    __syncthreads();
    for (int e = lo + t; e < hi; e += blockDim.x)
        atomicAdd(&hist[(rec[e].x >> 16) & 255], 1);
    __syncthreads();
    for (int off = 1; off < 256; off <<= 1) {
        int v = 0;
        if (t < 256 && t >= off) v = hist[t - off];
        __syncthreads();
        if (t < 256) hist[t] += v;
        __syncthreads();
    }
    if (t < 256) {
        pref[t] = t ? hist[t - 1] : 0;
        int node = b * 256 + t;
        if (node < N) row_ptr[node] = lo + pref[t];
    }
    __syncthreads();
    for (int e = lo + t; e < hi; e += blockDim.x) {
        int2 rc = rec[e];
        int dl = (rc.x >> 16) & 255;
        int r = atomicAdd(&cur[dl], 1);
        csr[lo + pref[dl] + r] = rc;
        atomicAdd(&degs[dl], __int_as_float(rc.y));
    }
    __syncthreads();
    if (t < 256) {
        int node = b * 256 + t;
        if (node < N) {
            float dg = degs[t];
            dinv[node] = (dg > 0.f) ? rsqrtf(dg) : 0.f;
        }
    }
}

// ---------------------------------------------------------------- MFMA GEMM: outb = bf16pack( dinv[row] * act(H) @ Wl )
__global__ __launch_bounds__(256, 2)
void gemm_mfma_kernel(const float* __restrict__ H, const float* __restrict__ Wl,
                      const float* __restrict__ AB, const float* __restrict__ dinv,
                      unsigned* __restrict__ outb, int n) {
    __shared__ __align__(16) unsigned short Wt[128][136];  // W^T, padded
    __shared__ __align__(16) unsigned short As[64][136];   // A tile, padded
    int t = threadIdx.x;
    int w = t >> 6, l = t & 63;
    int col16 = l & 15, grp = l >> 4;

    // stage W^T as bf16 (one time)
    for (int i = t; i < 128 * 128; i += 256) {
        int k = i >> 7, j = i & 127;
        Wt[j][k] = (unsigned short)(bf16pair(Wl[i], 0.f) & 0xFFFFu);
    }
    __syncthreads();

    // hoist B-fragments: 8 n-tiles x 4 k-blocks
    short8 bfrag[8][4];
    #pragma unroll
    for (int tt = 0; tt < 8; tt++)
        #pragma unroll
        for (int kb = 0; kb < 4; kb++)
            bfrag[tt][kb] = *(const short8*)&Wt[tt * 16 + col16][kb * 32 + grp * 8];

    int ntiles = (n + 63) >> 6;
    for (int tile = blockIdx.x; tile < ntiles; tile += gridDim.x) {
        int base = tile << 6;
        __syncthreads();   // prior a-frag reads done before overwrite
        // stage A: 64 rows x 128 cols, fused act, bf16 pack
        for (int i = t; i < 64 * 32; i += 256) {
            int rr = i >> 5, cc = (i & 31) * 4;
            int row = base + rr;
            float4 v = make_float4(0.f, 0.f, 0.f, 0.f);
            if (row < n) v = *(const float4*)(H + (size_t)row * D + cc);
            if (AB) {
                float4 A = *(const float4*)(AB + cc);
                float4 B = *(const float4*)(AB + 128 + cc);
                v.x = fmaxf(fmaf(v.x, A.x, B.x), 0.f);
                v.y = fmaxf(fmaf(v.y, A.y, B.y), 0.f);
                v.z = fmaxf(fmaf(v.z, A.z, B.z), 0.f);
                v.w = fmaxf(fmaf(v.w, A.w, B.w), 0.f);
            }
            *(uint2*)&As[rr][cc] = make_uint2(bf16pair(v.x, v.y), bf16pair(v.z, v.w));
        }
        __syncthreads();

        // a-fragments for this wave's 16 rows
        int rowb = w * 16;
        short8 afrag[4];
        #pragma unroll
        for (int kb = 0; kb < 4; kb++)
            afrag[kb] = *(const short8*)&As[rowb + col16][kb * 32 + grp * 8];

        // per-output-row dinv (fold src-side GCN norm into the table)
        float dv[4];
        #pragma unroll
        for (int r = 0; r < 4; r++) {
            int row = base + rowb + grp * 4 + r;
            dv[r] = (row < n) ? dinv[row] : 0.f;
        }

        #pragma unroll
        for (int tt = 0; tt < 8; tt++) {
            f32x4 acc = {0.f, 0.f, 0.f, 0.f};
            #pragma unroll
            for (int kb = 0; kb < 4; kb++)
                acc = __builtin_amdgcn_mfma_f32_16x16x32_bf16(afrag[kb], bfrag[tt][kb], acc, 0, 0, 0);
            #pragma unroll
            for (int r = 0; r < 4; r++) {
                float v = acc[r] * dv[r];
                float nb = __shfl_xor(v, 1);
                if (!(l & 1)) {
                    int row = base + rowb + grp * 4 + r;
                    if (row < n)
                        outb[(size_t)row * 64 + tt * 8 + (col16 >> 1)] = bf16pair(v, nb);
                }
            }
        }
    }
}

// ---------------------------------------------------------------- pull aggregation + bias + residual + col-stats
// R10-proven structure: contiguous row chunks, scalar-path csr batch loads,
// csr batch k+1 prefetched while batch k's gathers are in flight.
// hr accessed non-temporally to keep xlb resident in L2.
__global__ __launch_bounds__(256, 8)
void agg_kernel(const unsigned* __restrict__ xlb,
                const int* __restrict__ row_ptr,
                const int2* __restrict__ csr_ew,
                const float* __restrict__ dinv,
                const float* __restrict__ bvec,
                float* __restrict__ hr,        // in(res)/out, f32 (NT access)
                float* __restrict__ stats,     // [NSHARD][256]: sum | sumsq (atomic)
                int n, int has_res) {
    int wave = threadIdx.x >> 6;
    int lane = threadIdx.x & 63;
    int wid = blockIdx.x * 4 + wave;
    int nw = gridDim.x * 4;
    int chunk = (n + nw - 1) / nw;
    int r0 = wid * chunk;
    int r1 = r0 + chunk; if (r1 > n) r1 = n;

    float bb0 = bvec[lane * 2], bb1 = bvec[lane * 2 + 1];
    float s0 = 0.f, s1 = 0.f, q0 = 0.f, q1 = 0.f;

    for (int i = r0; i < r1; i++) {
        int beg = __builtin_amdgcn_readfirstlane(row_ptr[i]);
        int end = __builtin_amdgcn_readfirstlane(row_ptr[i + 1]);
        float di = __uint_as_float(
            (unsigned)__builtin_amdgcn_readfirstlane(__float_as_uint(dinv[i])));
        float pa0 = 0.f, pa1 = 0.f, pb0 = 0.f, pb1 = 0.f;
        float pc0 = 0.f, pc1 = 0.f, pd0 = 0.f, pd1 = 0.f;
        int nb = (end - beg) >> 3;           // full 8-edge batches
        int2 c0, c1, c2, c3, c4, c5, c6, c7;
        if (nb > 0) {
            c0 = csr_ew[beg + 0]; c1 = csr_ew[beg + 1];
            c2 = csr_ew[beg + 2]; c3 = csr_ew[beg + 3];
            c4 = csr_ew[beg + 4]; c5 = csr_ew[beg + 5];
            c6 = csr_ew[beg + 6]; c7 = csr_ew[beg + 7];
        }
        for (int k = 0; k < nb; k++) {
            // issue gathers for current batch
            unsigned g0 = xlb[(size_t)(c0.x & 0xFFFF) * 64 + lane];
            unsigned g1 = xlb[(size_t)(c1.x & 0xFFFF) * 64 + lane];
            unsigned g2 = xlb[(size_t)(c2.x & 0xFFFF) * 64 + lane];
            unsigned g3 = xlb[(size_t)(c3.x & 0xFFFF) * 64 + lane];
            unsigned g4 = xlb[(size_t)(c4.x & 0xFFFF) * 64 + lane];
            unsigned g5 = xlb[(size_t)(c5.x & 0xFFFF) * 64 + lane];
            unsigned g6 = xlb[(size_t)(c6.x & 0xFFFF) * 64 + lane];
            unsigned g7 = xlb[(size_t)(c7.x & 0xFFFF) * 64 + lane];
            float w0 = __int_as_float(c0.y), w1 = __int_as_float(c1.y);
            float w2 = __int_as_float(c2.y), w3 = __int_as_float(c3.y);
            float w4 = __int_as_float(c4.y), w5 = __int_as_float(c5.y);
            float w6 = __int_as_float(c6.y), w7 = __int_as_float(c7.y);
            // prefetch next batch's csr while gathers are in flight
            if (k + 1 < nb) {
                int eb = beg + (k + 1) * 8;
                c0 = csr_ew[eb + 0]; c1 = csr_ew[eb + 1];
                c2 = csr_ew[eb + 2]; c3 = csr_ew[eb + 3];
                c4 = csr_ew[eb + 4]; c5 = csr_ew[eb + 5];
                c6 = csr_ew[eb + 6]; c7 = csr_ew[eb + 7];
            }
            // consume gathers
            pa0 += w0 * __uint_as_float(g0 << 16); pa1 += w0 * __uint_as_float(g0 & 0xFFFF0000u);
            pb0 += w1 * __uint_as_float(g1 << 16); pb1 += w1 * __uint_as_float(g1 & 0xFFFF0000u);
            pc0 += w2 * __uint_as_float(g2 << 16); pc1 += w2 * __uint_as_float(g2 & 0xFFFF0000u);
            pd0 += w3 * __uint_as_float(g3 << 16); pd1 += w3 * __uint_as_float(g3 & 0xFFFF0000u);
            pa0 += w4 * __uint_as_float(g4 << 16); pa1 += w4 * __uint_as_float(g4 & 0xFFFF0000u);
            pb0 += w5 * __uint_as_float(g5 << 16); pb1 += w5 * __uint_as_float(g5 & 0xFFFF0000u);
            pc0 += w6 * __uint_as_float(g6 << 16); pc1 += w6 * __uint_as_float(g6 & 0xFFFF0000u);
            pd0 += w7 * __uint_as_float(g7 << 16); pd1 += w7 * __uint_as_float(g7 & 0xFFFF0000u);
        }
        for (int e = beg + nb * 8; e < end; e++) {
            int2 c = csr_ew[e];
            float wv = __int_as_float(c.y);
            unsigned g = xlb[(size_t)(c.x & 0xFFFF) * 64 + lane];
            pa0 += wv * __uint_as_float(g << 16);
            pa1 += wv * __uint_as_float(g & 0xFFFF0000u);
        }
        float a0 = ((pa0 + pb0) + (pc0 + pd0)) * di + bb0;
        float a1 = ((pa1 + pb1) + (pc1 + pd1)) * di + bb1;
        long long* hp = (long long*)(hr + (size_t)i * D + lane * 2);
        if (has_res) {
            long long rv = __builtin_nontemporal_load(hp);
            a0 += __uint_as_float((unsigned)(rv & 0xFFFFFFFFll));
            a1 += __uint_as_float((unsigned)((unsigned long long)rv >> 32));
        }
        long long sv = (long long)(((unsigned long long)__float_as_uint(a1) << 32) |
                                   (unsigned long long)__float_as_uint(a0));
        __builtin_nontemporal_store(sv, hp);
        s0 += a0; s1 += a1;
        q0 += a0 * a0; q1 += a1 * a1;
    }

    __shared__ float redS[4][D];
    __shared__ float redQ[4][D];
    redS[wave][lane * 2] = s0; redS[wave][lane * 2 + 1] = s1;
    redQ[wave][lane * 2] = q0; redQ[wave][lane * 2 + 1] = q1;
    __syncthreads();
    int t = threadIdx.x;
    float* sh = stats + (size_t)(blockIdx.x & (NSHARD - 1)) * 256;
    if (t < 128) {
        atomicAdd(&sh[t], redS[0][t] + redS[1][t] + redS[2][t] + redS[3][t]);
    } else {
        int c = t - 128;
        atomicAdd(&sh[128 + c], redQ[0][c] + redQ[1][c] + redQ[2][c] + redQ[3][c]);
    }
}

// ---------------------------------------------------------------- finalize stats (sum shards) -> per-col scale/shift
__global__ void finalize_kernel(const float* __restrict__ stats,
                                const float* __restrict__ gamma_l,
                                const float* __restrict__ beta_l,
                                float* __restrict__ AB, float n_inv) {
    int t = threadIdx.x; // 128
    if (t < 128) {
        float sum = 0.f, sq = 0.f;
        #pragma unroll
        for (int s = 0; s < NSHARD; s++) {
            sum += stats[s * 256 + t];
            sq  += stats[s * 256 + 128 + t];
        }
        float mean = sum * n_inv;
        float var  = sq * n_inv - mean * mean;
        var = fmaxf(var, 0.f);
        float rstd = rsqrtf(var + 1e-5f);
        float A = rstd * gamma_l[t];
        float B = beta_l[t] - mean * A;
        AB[t] = A;
        AB[128 + t] = B;
    }
}

// ---------------------------------------------------------------- normalize + relu (final layer only)
__global__ void norm_relu_kernel(const float* __restrict__ hr, const float* __restrict__ AB,
                                 float* __restrict__ hout, int total4) {
    int idx = blockIdx.x * blockDim.x + threadIdx.x;
    int stride = gridDim.x * blockDim.x;
    for (; idx < total4; idx += stride) {
        int c4 = (idx & 31) * 4;
        float4 v = ((const float4*)hr)[idx];
        float4 A = *(const float4*)(AB + c4);
        float4 B = *(const float4*)(AB + 128 + c4);
        v.x = fmaxf(fmaf(v.x, A.x, B.x), 0.f);
        v.y = fmaxf(fmaf(v.y, A.y, B.y), 0.f);
        v.z = fmaxf(fmaf(v.z, A.z, B.z), 0.f);
        v.w = fmaxf(fmaf(v.w, A.w, B.w), 0.f);
        ((float4*)hout)[idx] = v;
    }
}

// ================================================================ launch
extern "C" void kernel_launch(void* const* d_in, const int* in_sizes, int n_in,
                              void* d_out, int out_size, void* d_ws, size_t ws_size,
                              hipStream_t stream) {
    const float* x    = (const float*)d_in[0];
    const int*   eidx = (const int*)d_in[1];
    const float* ew   = (const float*)d_in[2];
    const float* W    = (const float*)d_in[3];
    const float* b    = (const float*)d_in[4];
    const float* gmm  = (const float*)d_in[5];
    const float* bet  = (const float*)d_in[6];

    const int N = in_sizes[0] / D;
    const int E = in_sizes[2];
    const int L = in_sizes[4] / D;
    const int NB = (N + 255) >> 8;
    const int NTILE = (N + 63) >> 6;

    size_t off = 0;
    auto carve = [&](size_t bytes) -> void* {
        void* p = (char*)d_ws + off;
        off += (bytes + 255) & ~(size_t)255;
        return p;
    };
    float*    dinv       = (float*)carve((size_t)N * 4);
    int*      row_ptr    = (int*)  carve((size_t)(N + 1) * 4);
    int*      bucket_cnt = (int*)  carve(256 * 4);
    int*      bucket_base= (int*)  carve(257 * 4);
    int*      bucket_cur = (int*)  carve(256 * 4);
    int2*     csr_ew     = (int2*) carve((size_t)E * 8);
    unsigned* xlb        = (unsigned*)carve((size_t)N * 64 * 4);
    float*    hr         = (float*)carve((size_t)N * D * 4);
    float*    stats      = (float*)carve((size_t)L * NSHARD * 256 * 4);
    float*    ABbuf      = (float*)carve((size_t)L * 256 * 4);
    if (off > ws_size) return;

    int2* rec = (int2*)hr;           // pass-1 intermediate overlays hr
    float* hout = (float*)d_out;

    hipMemsetAsync(bucket_cnt, 0, 256 * 4, stream);
    hipMemsetAsync(stats, 0, (size_t)L * NSHARD * 256 * 4, stream);
    hist_kernel<<<1024, 256, 0, stream>>>(eidx + E, bucket_cnt, E, N);
    bucket_scan_kernel<<<1, 256, 0, stream>>>(bucket_cnt, bucket_base, bucket_cur, row_ptr, N);
    pass1_kernel<<<1024, 256, 0, stream>>>(eidx, ew, bucket_cur, rec, E, N);
    pass2_kernel<<<NB, 1024, 0, stream>>>(rec, bucket_base, csr_ew, row_ptr, dinv, N);

    const float n_inv = 1.f / (float)N;
    for (int l = 0; l < L; l++) {
        const float* Hin = (l == 0) ? x : hr;
        const float* ABl = (l == 0) ? nullptr : ABbuf + (size_t)(l - 1) * 256;
        gemm_mfma_kernel<<<NTILE, 256, 0, stream>>>(Hin, W + (size_t)l * D * D, ABl, dinv, xlb, N);
        agg_kernel<<<AGG_BLOCKS, 256, 0, stream>>>(xlb, row_ptr, csr_ew, dinv,
                                                   b + (size_t)l * D, hr,
                                                   stats + (size_t)l * NSHARD * 256,
                                                   N, l > 0 ? 1 : 0);
        finalize_kernel<<<1, 128, 0, stream>>>(stats + (size_t)l * NSHARD * 256,
                                               gmm + (size_t)l * D, bet + (size_t)l * D,
                                               ABbuf + (size_t)l * 256, n_inv);
    }
    norm_relu_kernel<<<1024, 256, 0, stream>>>(hr, ABbuf + (size_t)(L - 1) * 256,
                                               hout, N * (D / 4));
}

// Round 14
// 338.022 us; speedup vs baseline: 1.1343x; 1.0253x over previous
//
#include <hip/hip_runtime.h>
#include <hip/hip_bf16.h>

#define D 128
#define AGG_BLOCKS 2048
#define NSHARD 16

typedef __attribute__((ext_vector_type(8))) short short8;
typedef __attribute__((ext_vector_type(4))) float f32x4;

// pack two f32 -> bf16 pair (RNE)
__device__ inline unsigned bf16pair(float x, float y) {
    unsigned xb = __float_as_uint(x), yb = __float_as_uint(y);
    xb = (xb + 0x7FFFu + ((xb >> 16) & 1u)) >> 16;
    yb = (yb + 0x7FFFu + ((yb >> 16) & 1u)) >> 16;
    return xb | (yb << 16);
}

// ---------------------------------------------------------------- pass 0: 256-bin histogram of dst>>8
__global__ void hist_kernel(const int* __restrict__ dst_idx,
                            int* __restrict__ bucket_cnt, int E, int N) {
    __shared__ int h[256];
    int t = threadIdx.x;
    h[t] = 0;
    __syncthreads();
    int e = blockIdx.x * blockDim.x + t;
    int stride = gridDim.x * blockDim.x;
    for (; e < E; e += stride) {
        int d = dst_idx[e];
        if ((unsigned)d < (unsigned)N) atomicAdd(&h[d >> 8], 1);
    }
    __syncthreads();
    if (h[t]) atomicAdd(&bucket_cnt[t], h[t]);
}

// ---------------------------------------------------------------- scan 256 buckets
__global__ void bucket_scan_kernel(const int* __restrict__ bucket_cnt,
                                   int* __restrict__ bucket_base,
                                   int* __restrict__ bucket_cursor,
                                   int* __restrict__ row_ptr, int N) {
    __shared__ int s[256];
    int t = threadIdx.x;
    s[t] = bucket_cnt[t];
    __syncthreads();
    for (int off = 1; off < 256; off <<= 1) {
        int v = (t >= off) ? s[t - off] : 0;
        __syncthreads();
        s[t] += v;
        __syncthreads();
    }
    int ex = t ? s[t - 1] : 0;
    bucket_base[t]   = ex;
    bucket_cursor[t] = ex;
    if (t == 255) { bucket_base[256] = s[255]; row_ptr[N] = s[255]; }
}

// ---------------------------------------------------------------- pass 1: chunked scatter into coarse buckets
#define CH 1024
__global__ void pass1_kernel(const int* __restrict__ idx,
                             const float* __restrict__ w,
                             int* __restrict__ bucket_cursor,
                             int2* __restrict__ rec, int E, int N) {
    __shared__ int h[256], bb[256], cur[256];
    const int* dst = idx + E;
    int t = threadIdx.x;
    int nchunks = (E + CH - 1) / CH;
    for (int c = blockIdx.x; c < nchunks; c += gridDim.x) {
        int lo = c * CH;
        int hi = lo + CH; if (hi > E) hi = E;
        h[t] = 0; cur[t] = 0;
        __syncthreads();
        for (int e = lo + t; e < hi; e += 256) {
            int d = dst[e];
            if ((unsigned)d < (unsigned)N) atomicAdd(&h[d >> 8], 1);
        }
        __syncthreads();
        if (h[t]) bb[t] = atomicAdd(&bucket_cursor[t], h[t]);
        __syncthreads();
        for (int e = lo + t; e < hi; e += 256) {
            int d = dst[e];
            if ((unsigned)d >= (unsigned)N) continue;
            int s = idx[e];
            int b = d >> 8;
            int r = atomicAdd(&cur[b], 1);
            rec[bb[b] + r] = make_int2((s & 0xFFFF) | ((d & 255) << 16),
                                       __float_as_int(w[e]));
        }
        __syncthreads();
    }
}

// ---------------------------------------------------------------- pass 2: per-bucket LDS counting sort -> CSR (u16 src | bf16 w) + row_ptr + dinv
__global__ void pass2_kernel(const int2* __restrict__ rec,
                             const int* __restrict__ bucket_base,
                             unsigned* __restrict__ csr,
                             int* __restrict__ row_ptr,
                             float* __restrict__ dinv, int N) {
    __shared__ int   hist[256], pref[256], cur[256];
    __shared__ float degs[256];
    int b = blockIdx.x;
    int t = threadIdx.x;
    int lo = bucket_base[b], hi = bucket_base[b + 1];
    if (t < 256) { hist[t] = 0; cur[t] = 0; degs[t] = 0.f; }
    __syncthreads();
    for (int e = lo + t; e < hi; e += blockDim.x)
        atomicAdd(&hist[(rec[e].x >> 16) & 255], 1);
    __syncthreads();
    for (int off = 1; off < 256; off <<= 1) {
        int v = 0;
        if (t < 256 && t >= off) v = hist[t - off];
        __syncthreads();
        if (t < 256) hist[t] += v;
        __syncthreads();
    }
    if (t < 256) {
        pref[t] = t ? hist[t - 1] : 0;
        int node = b * 256 + t;
        if (node < N) row_ptr[node] = lo + pref[t];
    }
    __syncthreads();
    for (int e = lo + t; e < hi; e += blockDim.x) {
        int2 rc = rec[e];
        int dl = (rc.x >> 16) & 255;
        int r = atomicAdd(&cur[dl], 1);
        float wv = __int_as_float(rc.y);
        csr[lo + pref[dl] + r] = (unsigned)(rc.x & 0xFFFF) | (bf16pair(wv, 0.f) << 16);
        atomicAdd(&degs[dl], wv);
    }
    __syncthreads();
    if (t < 256) {
        int node = b * 256 + t;
        if (node < N) {
            float dg = degs[t];
            dinv[node] = (dg > 0.f) ? rsqrtf(dg) : 0.f;
        }
    }
}

// ---------------------------------------------------------------- MFMA GEMM: outb = bf16pack( dinv[row] * act(H) @ Wl )
// act: identity (stats==nullptr) or fused BN+ReLU with AB computed in-block from sharded stats.
__global__ __launch_bounds__(256, 2)
void gemm_mfma_kernel(const float* __restrict__ H, const float* __restrict__ Wl,
                      const float* __restrict__ stats,
                      const float* __restrict__ gamma_l,
                      const float* __restrict__ beta_l,
                      const float* __restrict__ dinv,
                      unsigned* __restrict__ outb, int n, float n_inv) {
    __shared__ __align__(16) unsigned short Wt[128][136];  // W^T, padded
    __shared__ __align__(16) unsigned short As[64][136];   // A tile, padded
    __shared__ float ABs[256];
    int t = threadIdx.x;
    int w = t >> 6, l = t & 63;
    int col16 = l & 15, grp = l >> 4;

    // finalize BN stats -> per-col scale/shift (redundant per block, tiny)
    if (stats && t < 128) {
        float sum = 0.f, sq = 0.f;
        #pragma unroll
        for (int s = 0; s < NSHARD; s++) {
            sum += stats[s * 256 + t];
            sq  += stats[s * 256 + 128 + t];
        }
        float mean = sum * n_inv;
        float var  = fmaxf(sq * n_inv - mean * mean, 0.f);
        float rstd = rsqrtf(var + 1e-5f);
        float A = rstd * gamma_l[t];
        ABs[t] = A;
        ABs[128 + t] = beta_l[t] - mean * A;
    }

    // stage W^T as bf16 (one time)
    for (int i = t; i < 128 * 128; i += 256) {
        int k = i >> 7, j = i & 127;
        Wt[j][k] = (unsigned short)(bf16pair(Wl[i], 0.f) & 0xFFFFu);
    }
    __syncthreads();

    // hoist B-fragments: 8 n-tiles x 4 k-blocks
    short8 bfrag[8][4];
    #pragma unroll
    for (int tt = 0; tt < 8; tt++)
        #pragma unroll
        for (int kb = 0; kb < 4; kb++)
            bfrag[tt][kb] = *(const short8*)&Wt[tt * 16 + col16][kb * 32 + grp * 8];

    int ntiles = (n + 63) >> 6;
    for (int tile = blockIdx.x; tile < ntiles; tile += gridDim.x) {
        int base = tile << 6;
        __syncthreads();   // prior a-frag reads done before overwrite
        // stage A: 64 rows x 128 cols, fused act, bf16 pack
        for (int i = t; i < 64 * 32; i += 256) {
            int rr = i >> 5, cc = (i & 31) * 4;
            int row = base + rr;
            float4 v = make_float4(0.f, 0.f, 0.f, 0.f);
            if (row < n) v = *(const float4*)(H + (size_t)row * D + cc);
            if (stats) {
                float4 A = *(const float4*)(ABs + cc);
                float4 B = *(const float4*)(ABs + 128 + cc);
                v.x = fmaxf(fmaf(v.x, A.x, B.x), 0.f);
                v.y = fmaxf(fmaf(v.y, A.y, B.y), 0.f);
                v.z = fmaxf(fmaf(v.z, A.z, B.z), 0.f);
                v.w = fmaxf(fmaf(v.w, A.w, B.w), 0.f);
            }
            *(uint2*)&As[rr][cc] = make_uint2(bf16pair(v.x, v.y), bf16pair(v.z, v.w));
        }
        __syncthreads();

        // a-fragments for this wave's 16 rows
        int rowb = w * 16;
        short8 afrag[4];
        #pragma unroll
        for (int kb = 0; kb < 4; kb++)
            afrag[kb] = *(const short8*)&As[rowb + col16][kb * 32 + grp * 8];

        // per-output-row dinv (fold src-side GCN norm into the table)
        float dv[4];
        #pragma unroll
        for (int r = 0; r < 4; r++) {
            int row = base + rowb + grp * 4 + r;
            dv[r] = (row < n) ? dinv[row] : 0.f;
        }

        #pragma unroll
        for (int tt = 0; tt < 8; tt++) {
            f32x4 acc = {0.f, 0.f, 0.f, 0.f};
            #pragma unroll
            for (int kb = 0; kb < 4; kb++)
                acc = __builtin_amdgcn_mfma_f32_16x16x32_bf16(afrag[kb], bfrag[tt][kb], acc, 0, 0, 0);
            #pragma unroll
            for (int r = 0; r < 4; r++) {
                float v = acc[r] * dv[r];
                float nb = __shfl_xor(v, 1);
                if (!(l & 1)) {
                    int row = base + rowb + grp * 4 + r;
                    if (row < n)
                        outb[(size_t)row * 64 + tt * 8 + (col16 >> 1)] = bf16pair(v, nb);
                }
            }
        }
    }
}

// ---------------------------------------------------------------- pull aggregation + bias + residual + col-stats
// R10 structure widened to 16 gathers in flight; csr entries 4B (u16 src | bf16 w) on the scalar path.
#define LD16(eb) \
    u0 = csr_ew[(eb) + 0];  u1 = csr_ew[(eb) + 1];  u2 = csr_ew[(eb) + 2];  u3 = csr_ew[(eb) + 3]; \
    u4 = csr_ew[(eb) + 4];  u5 = csr_ew[(eb) + 5];  u6 = csr_ew[(eb) + 6];  u7 = csr_ew[(eb) + 7]; \
    u8 = csr_ew[(eb) + 8];  u9 = csr_ew[(eb) + 9];  u10 = csr_ew[(eb) + 10]; u11 = csr_ew[(eb) + 11]; \
    u12 = csr_ew[(eb) + 12]; u13 = csr_ew[(eb) + 13]; u14 = csr_ew[(eb) + 14]; u15 = csr_ew[(eb) + 15];
#define G16() \
    g0 = xlb[(size_t)(u0 & 0xFFFFu) * 64 + lane];   g1 = xlb[(size_t)(u1 & 0xFFFFu) * 64 + lane]; \
    g2 = xlb[(size_t)(u2 & 0xFFFFu) * 64 + lane];   g3 = xlb[(size_t)(u3 & 0xFFFFu) * 64 + lane]; \
    g4 = xlb[(size_t)(u4 & 0xFFFFu) * 64 + lane];   g5 = xlb[(size_t)(u5 & 0xFFFFu) * 64 + lane]; \
    g6 = xlb[(size_t)(u6 & 0xFFFFu) * 64 + lane];   g7 = xlb[(size_t)(u7 & 0xFFFFu) * 64 + lane]; \
    g8 = xlb[(size_t)(u8 & 0xFFFFu) * 64 + lane];   g9 = xlb[(size_t)(u9 & 0xFFFFu) * 64 + lane]; \
    g10 = xlb[(size_t)(u10 & 0xFFFFu) * 64 + lane]; g11 = xlb[(size_t)(u11 & 0xFFFFu) * 64 + lane]; \
    g12 = xlb[(size_t)(u12 & 0xFFFFu) * 64 + lane]; g13 = xlb[(size_t)(u13 & 0xFFFFu) * 64 + lane]; \
    g14 = xlb[(size_t)(u14 & 0xFFFFu) * 64 + lane]; g15 = xlb[(size_t)(u15 & 0xFFFFu) * 64 + lane];
#define WD16() \
    w0 = __uint_as_float(u0 & 0xFFFF0000u);  w1 = __uint_as_float(u1 & 0xFFFF0000u); \
    w2 = __uint_as_float(u2 & 0xFFFF0000u);  w3 = __uint_as_float(u3 & 0xFFFF0000u); \
    w4 = __uint_as_float(u4 & 0xFFFF0000u);  w5 = __uint_as_float(u5 & 0xFFFF0000u); \
    w6 = __uint_as_float(u6 & 0xFFFF0000u);  w7 = __uint_as_float(u7 & 0xFFFF0000u); \
    w8 = __uint_as_float(u8 & 0xFFFF0000u);  w9 = __uint_as_float(u9 & 0xFFFF0000u); \
    w10 = __uint_as_float(u10 & 0xFFFF0000u); w11 = __uint_as_float(u11 & 0xFFFF0000u); \
    w12 = __uint_as_float(u12 & 0xFFFF0000u); w13 = __uint_as_float(u13 & 0xFFFF0000u); \
    w14 = __uint_as_float(u14 & 0xFFFF0000u); w15 = __uint_as_float(u15 & 0xFFFF0000u);
#define C1(g, wf, A) { \
    A##0 += (wf) * __uint_as_float((g) << 16); \
    A##1 += (wf) * __uint_as_float((g) & 0xFFFF0000u); }
#define CONS16() \
    C1(g0, w0, pa)  C1(g1, w1, pb)  C1(g2, w2, pc)  C1(g3, w3, pd) \
    C1(g4, w4, pa)  C1(g5, w5, pb)  C1(g6, w6, pc)  C1(g7, w7, pd) \
    C1(g8, w8, pa)  C1(g9, w9, pb)  C1(g10, w10, pc) C1(g11, w11, pd) \
    C1(g12, w12, pa) C1(g13, w13, pb) C1(g14, w14, pc) C1(g15, w15, pd)

__global__ __launch_bounds__(256, 8)
void agg_kernel(const unsigned* __restrict__ xlb,
                const int* __restrict__ row_ptr,
                const unsigned* __restrict__ csr_ew,
                const float* __restrict__ dinv,
                const float* __restrict__ bvec,
                float* __restrict__ hr,        // in(res)/out, f32 (NT access)
                float* __restrict__ stats,     // [NSHARD][256]: sum | sumsq (atomic)
                int n, int has_res) {
    int wave = threadIdx.x >> 6;
    int lane = threadIdx.x & 63;
    int wid = blockIdx.x * 4 + wave;
    int nw = gridDim.x * 4;
    int chunk = (n + nw - 1) / nw;
    int r0 = wid * chunk;
    int r1 = r0 + chunk; if (r1 > n) r1 = n;

    float bb0 = bvec[lane * 2], bb1 = bvec[lane * 2 + 1];
    float s0 = 0.f, s1 = 0.f, q0 = 0.f, q1 = 0.f;

    for (int i = r0; i < r1; i++) {
        int beg = __builtin_amdgcn_readfirstlane(row_ptr[i]);
        int end = __builtin_amdgcn_readfirstlane(row_ptr[i + 1]);
        float di = __uint_as_float(
            (unsigned)__builtin_amdgcn_readfirstlane(__float_as_uint(dinv[i])));
        float pa0 = 0.f, pa1 = 0.f, pb0 = 0.f, pb1 = 0.f;
        float pc0 = 0.f, pc1 = 0.f, pd0 = 0.f, pd1 = 0.f;
        int nb = (end - beg) >> 4;           // full 16-edge batches
        unsigned u0, u1, u2, u3, u4, u5, u6, u7;
        unsigned u8, u9, u10, u11, u12, u13, u14, u15;
        unsigned g0, g1, g2, g3, g4, g5, g6, g7;
        unsigned g8, g9, g10, g11, g12, g13, g14, g15;
        float w0, w1, w2, w3, w4, w5, w6, w7;
        float w8, w9, w10, w11, w12, w13, w14, w15;
        if (nb > 0) { LD16(beg) }
        for (int k = 0; k < nb; k++) {
            G16()                 // issue 16 gathers
            WD16()                // decode weights from scalar regs
            if (k + 1 < nb) { LD16(beg + (k + 1) * 16) }   // prefetch next csr batch
            CONS16()              // consume as gathers land
        }
        int e = beg + nb * 16;
        if (end - e >= 8) {       // one 8-edge mid-batch
            u0 = csr_ew[e + 0]; u1 = csr_ew[e + 1]; u2 = csr_ew[e + 2]; u3 = csr_ew[e + 3];
            u4 = csr_ew[e + 4]; u5 = csr_ew[e + 5]; u6 = csr_ew[e + 6]; u7 = csr_ew[e + 7];
            g0 = xlb[(size_t)(u0 & 0xFFFFu) * 64 + lane]; g1 = xlb[(size_t)(u1 & 0xFFFFu) * 64 + lane];
            g2 = xlb[(size_t)(u2 & 0xFFFFu) * 64 + lane]; g3 = xlb[(size_t)(u3 & 0xFFFFu) * 64 + lane];
            g4 = xlb[(size_t)(u4 & 0xFFFFu) * 64 + lane]; g5 = xlb[(size_t)(u5 & 0xFFFFu) * 64 + lane];
            g6 = xlb[(size_t)(u6 & 0xFFFFu) * 64 + lane]; g7 = xlb[(size_t)(u7 & 0xFFFFu) * 64 + lane];
            w0 = __uint_as_float(u0 & 0xFFFF0000u); w1 = __uint_as_float(u1 & 0xFFFF0000u);
            w2 = __uint_as_float(u2 & 0xFFFF0000u); w3 = __uint_as_float(u3 & 0xFFFF0000u);
            w4 = __uint_as_float(u4 & 0xFFFF0000u); w5 = __uint_as_float(u5 & 0xFFFF0000u);
            w6 = __uint_as_float(u6 & 0xFFFF0000u); w7 = __uint_as_float(u7 & 0xFFFF0000u);
            C1(g0, w0, pa) C1(g1, w1, pb) C1(g2, w2, pc) C1(g3, w3, pd)
            C1(g4, w4, pa) C1(g5, w5, pb) C1(g6, w6, pc) C1(g7, w7, pd)
            e += 8;
        }
        for (; e < end; e++) {
            unsigned u = csr_ew[e];
            float wv = __uint_as_float(u & 0xFFFF0000u);
            unsigned g = xlb[(size_t)(u & 0xFFFFu) * 64 + lane];
            pa0 += wv * __uint_as_float(g << 16);
            pa1 += wv * __uint_as_float(g & 0xFFFF0000u);
        }
        float a0 = ((pa0 + pb0) + (pc0 + pd0)) * di + bb0;
        float a1 = ((pa1 + pb1) + (pc1 + pd1)) * di + bb1;
        long long* hp = (long long*)(hr + (size_t)i * D + lane * 2);
        if (has_res) {
            long long rv = __builtin_nontemporal_load(hp);
            a0 += __uint_as_float((unsigned)(rv & 0xFFFFFFFFll));
            a1 += __uint_as_float((unsigned)((unsigned long long)rv >> 32));
        }
        long long sv = (long long)(((unsigned long long)__float_as_uint(a1) << 32) |
                                   (unsigned long long)__float_as_uint(a0));
        __builtin_nontemporal_store(sv, hp);
        s0 += a0; s1 += a1;
        q0 += a0 * a0; q1 += a1 * a1;
    }

    __shared__ float redS[4][D];
    __shared__ float redQ[4][D];
    redS[wave][lane * 2] = s0; redS[wave][lane * 2 + 1] = s1;
    redQ[wave][lane * 2] = q0; redQ[wave][lane * 2 + 1] = q1;
    __syncthreads();
    int t = threadIdx.x;
    float* sh = stats + (size_t)(blockIdx.x & (NSHARD - 1)) * 256;
    if (t < 128) {
        atomicAdd(&sh[t], redS[0][t] + redS[1][t] + redS[2][t] + redS[3][t]);
    } else {
        int c = t - 128;
        atomicAdd(&sh[128 + c], redQ[0][c] + redQ[1][c] + redQ[2][c] + redQ[3][c]);
    }
}

// ---------------------------------------------------------------- normalize + relu (final layer; AB computed in-block)
__global__ void norm_relu_kernel(const float* __restrict__ hr,
                                 const float* __restrict__ stats,
                                 const float* __restrict__ gamma_l,
                                 const float* __restrict__ beta_l,
                                 float* __restrict__ hout, int total4, float n_inv) {
    __shared__ float ABs[256];
    int t = threadIdx.x;
    if (t < 128) {
        float sum = 0.f, sq = 0.f;
        #pragma unroll
        for (int s = 0; s < NSHARD; s++) {
            sum += stats[s * 256 + t];
            sq  += stats[s * 256 + 128 + t];
        }
        float mean = sum * n_inv;
        float var  = fmaxf(sq * n_inv - mean * mean, 0.f);
        float rstd = rsqrtf(var + 1e-5f);
        float A = rstd * gamma_l[t];
        ABs[t] = A;
        ABs[128 + t] = beta_l[t] - mean * A;
    }
    __syncthreads();
    int idx = blockIdx.x * blockDim.x + t;
    int stride = gridDim.x * blockDim.x;
    for (; idx < total4; idx += stride) {
        int c4 = (idx & 31) * 4;
        float4 v = ((const float4*)hr)[idx];
        float4 A = *(const float4*)(ABs + c4);
        float4 B = *(const float4*)(ABs + 128 + c4);
        v.x = fmaxf(fmaf(v.x, A.x, B.x), 0.f);
        v.y = fmaxf(fmaf(v.y, A.y, B.y), 0.f);
        v.z = fmaxf(fmaf(v.z, A.z, B.z), 0.f);
        v.w = fmaxf(fmaf(v.w, A.w, B.w), 0.f);
        ((float4*)hout)[idx] = v;
    }
}

// ================================================================ launch
extern "C" void kernel_launch(void* const* d_in, const int* in_sizes, int n_in,
                              void* d_out, int out_size, void* d_ws, size_t ws_size,
                              hipStream_t stream) {
    const float* x    = (const float*)d_in[0];
    const int*   eidx = (const int*)d_in[1];
    const float* ew   = (const float*)d_in[2];
    const float* W    = (const float*)d_in[3];
    const float* b    = (const float*)d_in[4];
    const float* gmm  = (const float*)d_in[5];
    const float* bet  = (const float*)d_in[6];

    const int N = in_sizes[0] / D;
    const int E = in_sizes[2];
    const int L = in_sizes[4] / D;
    const int NB = (N + 255) >> 8;
    const int NTILE = (N + 63) >> 6;

    size_t off = 0;
    auto carve = [&](size_t bytes) -> void* {
        void* p = (char*)d_ws + off;
        off += (bytes + 255) & ~(size_t)255;
        return p;
    };
    float*    dinv       = (float*)carve((size_t)N * 4);
    int*      row_ptr    = (int*)  carve((size_t)(N + 1) * 4);
    int*      bucket_cnt = (int*)  carve(256 * 4);
    int*      bucket_base= (int*)  carve(257 * 4);
    int*      bucket_cur = (int*)  carve(256 * 4);
    unsigned* csr_ew     = (unsigned*)carve((size_t)E * 4);
    int2*     rec        = (int2*) carve((size_t)E * 8);
    unsigned* xlb        = (unsigned*)carve((size_t)N * 64 * 4);
    float*    hr         = (float*)carve((size_t)N * D * 4);
    float*    stats      = (float*)carve((size_t)L * NSHARD * 256 * 4);
    if (off > ws_size) return;

    float* hout = (float*)d_out;

    hipMemsetAsync(bucket_cnt, 0, 256 * 4, stream);
    hipMemsetAsync(stats, 0, (size_t)L * NSHARD * 256 * 4, stream);
    hist_kernel<<<1024, 256, 0, stream>>>(eidx + E, bucket_cnt, E, N);
    bucket_scan_kernel<<<1, 256, 0, stream>>>(bucket_cnt, bucket_base, bucket_cur, row_ptr, N);
    pass1_kernel<<<1024, 256, 0, stream>>>(eidx, ew, bucket_cur, rec, E, N);
    pass2_kernel<<<NB, 1024, 0, stream>>>(rec, bucket_base, csr_ew, row_ptr, dinv, N);

    const float n_inv = 1.f / (float)N;
    for (int l = 0; l < L; l++) {
        const float* Hin = (l == 0) ? x : hr;
        const float* st  = (l == 0) ? nullptr : stats + (size_t)(l - 1) * NSHARD * 256;
        gemm_mfma_kernel<<<NTILE, 256, 0, stream>>>(Hin, W + (size_t)l * D * D,
                                                    st, gmm + (size_t)(l ? l - 1 : 0) * D,
                                                    bet + (size_t)(l ? l - 1 : 0) * D,
                                                    dinv, xlb, N, n_inv);
        agg_kernel<<<AGG_BLOCKS, 256, 0, stream>>>(xlb, row_ptr, csr_ew, dinv,
                                                   b + (size_t)l * D, hr,
                                                   stats + (size_t)l * NSHARD * 256,
                                                   N, l > 0 ? 1 : 0);
    }
    norm_relu_kernel<<<1024, 256, 0, stream>>>(hr, stats + (size_t)(L - 1) * NSHARD * 256,
                                               gmm + (size_t)(L - 1) * D, bet + (size_t)(L - 1) * D,
                                               hout, N * (D / 4), n_inv);
}